// Round 12
// baseline (121.614 us; speedup 1.0000x reference)
//
#include <hip/hip_runtime.h>
#include <stdint.h>

#define N_PTS 256

typedef unsigned long long ull;
typedef float v2f __attribute__((ext_vector_type(2)));

__device__ __forceinline__ unsigned umin2(unsigned a, unsigned b) { return a < b ? a : b; }

// Single-inst DPP max stage (old=0 + bound_ctrl=1 = unsigned-max identity ->
// GCNDPPCombine folds to one v_max_u32_dpp; verified R7).
template<int CTRL>
__device__ __forceinline__ unsigned dppmax(unsigned x) {
    unsigned y = (unsigned)__builtin_amdgcn_update_dpp(0, (int)x, CTRL, 0xf, 0xf, true);
    return x > y ? x : y;
}

// Wave MIN via complemented unsigned MAX (bit-exact; NaN sinks). Single chain.
__device__ __forceinline__ unsigned wave_cmax1(float m) {
    unsigned c = ~__float_as_uint(m);
    c = dppmax<0x121>(c); c = dppmax<0x122>(c); c = dppmax<0x124>(c);
    c = dppmax<0x128>(c); c = dppmax<0x142>(c); c = dppmax<0x143>(c);
    return ~((unsigned)__builtin_amdgcn_readlane((int)c, 63));
}

// Two independent chains, zipped stage-by-stage.
__device__ __forceinline__ void wave_cmax2(float mA, float mB,
                                           unsigned& muA, unsigned& muB) {
    unsigned a = ~__float_as_uint(mA);
    unsigned b = ~__float_as_uint(mB);
    a = dppmax<0x121>(a); b = dppmax<0x121>(b);
    a = dppmax<0x122>(a); b = dppmax<0x122>(b);
    a = dppmax<0x124>(a); b = dppmax<0x124>(b);
    a = dppmax<0x128>(a); b = dppmax<0x128>(b);
    a = dppmax<0x142>(a); b = dppmax<0x142>(b);
    a = dppmax<0x143>(a); b = dppmax<0x143>(b);
    muA = ~((unsigned)__builtin_amdgcn_readlane((int)a, 63));
    muB = ~((unsigned)__builtin_amdgcn_readlane((int)b, 63));
}

__device__ __forceinline__ unsigned argmin_ballots(
    float d0, float d1, float d2, float d3, float ms) {
    ull e0 = __ballot(d0 == ms);
    ull e1 = __ballot(d1 == ms);
    ull e2 = __ballot(d2 == ms);
    ull e3 = __ballot(d3 == ms);
    unsigned u0 = (unsigned)(__ffsll((long long)e0) - 1);
    unsigned u1 = ((unsigned)(__ffsll((long long)e1) - 1)) | 64u;
    unsigned u2 = ((unsigned)(__ffsll((long long)e2) - 1)) | 128u;
    unsigned u3 = ((unsigned)(__ffsll((long long)e3) - 1)) | 192u;
    return umin2(umin2(u0, u1), umin2(u2, u3));
}

__device__ __forceinline__ void poison(unsigned k, unsigned lane, float vNAN,
                                       v2f& p0, v2f& p1, v2f& p2, v2f& p3) {
    unsigned ks = k >> 6, kl = k & 63u;
    bool hit = (lane == kl);
    p0.x = (hit && ks == 0) ? vNAN : p0.x;
    p1.x = (hit && ks == 1) ? vNAN : p1.x;
    p2.x = (hit && ks == 2) ? vNAN : p2.x;
    p3.x = (hit && ks == 3) ? vNAN : p3.x;
}

// One 64-target phase as 32 speculative PAIRS over the pre-A set (validated
// absmax 0.0 in R3/R9). The whole pair round is zipped A/B at source so the
// two ~630-cyc dependency chains overlap; __launch_bounds__(256,2) gives the
// RA a 256-VGPR budget so it need not serialize them (the R3/R9 suspect).
__device__ __forceinline__ void phase(
    float txc, float tyc, unsigned lane, float& acc,
    v2f& p0, v2f& p1, v2f& p2, v2f& p3, float vNAN)
{
    #pragma clang fp contract(off)
    const unsigned BIG_U = __float_as_uint(66049.0f); // 257^2
    #pragma unroll 1
    for (int j = 0; j < 64; j += 2) {
        float tAx = __int_as_float(__builtin_amdgcn_readlane(__float_as_int(txc), j));
        float tAy = __int_as_float(__builtin_amdgcn_readlane(__float_as_int(tyc), j));
        float tBx = __int_as_float(__builtin_amdgcn_readlane(__float_as_int(txc), j + 1));
        float tBy = __int_as_float(__builtin_amdgcn_readlane(__float_as_int(tyc), j + 1));

        // distances for BOTH targets, zipped (contract off: bit-exact vs ref)
        v2f tA; tA.x = tAx; tA.y = tAy;
        v2f tB; tB.x = tBx; tB.y = tBy;
        v2f qA0 = tA - p0;  v2f qB0 = tB - p0;
        v2f qA1 = tA - p1;  v2f qB1 = tB - p1;
        v2f qA2 = tA - p2;  v2f qB2 = tB - p2;
        v2f qA3 = tA - p3;  v2f qB3 = tB - p3;
        v2f sA0 = qA0 * qA0; v2f sB0 = qB0 * qB0;
        v2f sA1 = qA1 * qA1; v2f sB1 = qB1 * qB1;
        v2f sA2 = qA2 * qA2; v2f sB2 = qB2 * qB2;
        v2f sA3 = qA3 * qA3; v2f sB3 = qB3 * qB3;
        float dA0 = sA0.x + sA0.y;  float dB0 = sB0.x + sB0.y;
        float dA1 = sA1.x + sA1.y;  float dB1 = sB1.x + sB1.y;
        float dA2 = sA2.x + sA2.y;  float dB2 = sB2.x + sB2.y;
        float dA3 = sA3.x + sA3.y;  float dB3 = sB3.x + sB3.y;

        float mA = fminf(fminf(dA0, dA1), fminf(dA2, dA3));
        float mB = fminf(fminf(dB0, dB1), fminf(dB2, dB3));
        unsigned muA, muB;
        wave_cmax2(mA, mB, muA, muB);
        float msA = __uint_as_float(muA);
        float msB = __uint_as_float(muB);

        unsigned kA = argmin_ballots(dA0, dA1, dA2, dA3, msA);
        unsigned kB = argmin_ballots(dB0, dB1, dB2, dB3, msB);

        // resolve A exactly (k=0 claim when mA >= BIG, matching reference)
        bool okA = (muA < BIG_U);
        kA = okA ? kA : 0u;
        acc += __uint_as_float(umin2(muA, BIG_U));
        poison(kA, lane, vNAN, p0, p1, p2, p3);

        // B valid unless its pick was just consumed by A (wave-uniform redo)
        if (kB == kA) {
            v2f r0 = tB - p0, r1 = tB - p1, r2 = tB - p2, r3 = tB - p3;
            v2f w0 = r0 * r0, w1 = r1 * r1, w2 = r2 * r2, w3 = r3 * r3;
            float f0 = w0.x + w0.y, f1 = w1.x + w1.y;
            float f2 = w2.x + w2.y, f3 = w3.x + w3.y;
            float m2 = fminf(fminf(f0, f1), fminf(f2, f3));
            muB = wave_cmax1(m2);
            kB = argmin_ballots(f0, f1, f2, f3, __uint_as_float(muB));
        }
        bool okB = (muB < BIG_U);
        kB = okB ? kB : 0u;
        acc += __uint_as_float(umin2(muB, BIG_U));
        poison(kB, lane, vNAN, p0, p1, p2, p3);
    }
}

// One wave per batch, 2 waves/SIMD; (256,2) -> 256-VGPR budget per wave so
// the paired chains can stay live simultaneously.
__global__ __launch_bounds__(256, 2) void greedy_match_kernel(
    const float* __restrict__ input,
    const float* __restrict__ targets,
    float* __restrict__ out,
    int B, float scale)
{
    __shared__ float wsum[4];
    const unsigned lane = threadIdx.x & 63;
    const int wid  = threadIdx.x >> 6;
    const int b    = blockIdx.x * 4 + wid;

    float acc = 0.0f;
    if (b < B) {
        const v2f* pin = (const v2f*)(input   + (size_t)b * (2 * N_PTS));
        const v2f* ptg = (const v2f*)(targets + (size_t)b * (2 * N_PTS));

        v2f p0 = pin[lane],       p1 = pin[64 + lane];
        v2f p2 = pin[128 + lane], p3 = pin[192 + lane];
        v2f t0 = ptg[lane],       t1 = ptg[64 + lane];
        v2f t2 = ptg[128 + lane], t3 = ptg[192 + lane];

        const float vNAN = __int_as_float(0x7fc00000);

        phase(t0.x, t0.y, lane, acc, p0, p1, p2, p3, vNAN);
        phase(t1.x, t1.y, lane, acc, p0, p1, p2, p3, vNAN);
        phase(t2.x, t2.y, lane, acc, p0, p1, p2, p3, vNAN);
        phase(t3.x, t3.y, lane, acc, p0, p1, p2, p3, vNAN);
    }

    if (lane == 0) wsum[wid] = acc;
    __syncthreads();
    if (threadIdx.x == 0) {
        float s = (wsum[0] + wsum[1] + wsum[2] + wsum[3]) * scale;
        atomicAdd(out, s);
    }
}

extern "C" void kernel_launch(void* const* d_in, const int* in_sizes, int n_in,
                              void* d_out, int out_size, void* d_ws, size_t ws_size,
                              hipStream_t stream) {
    const float* input   = (const float*)d_in[0];
    const float* targets = (const float*)d_in[1];
    float* out = (float*)d_out;

    const int B = in_sizes[0] / (2 * N_PTS);
    const float scale = 1.0f / ((float)B * (float)(2 * N_PTS));

    // d_out is poisoned 0xAA before every call — zero it (graph-capturable).
    hipMemsetAsync(d_out, 0, sizeof(float) * (size_t)out_size, stream);

    const int blocks = (B + 3) / 4;  // 4 waves (4 batches) per 256-thread block
    greedy_match_kernel<<<blocks, 256, 0, stream>>>(input, targets, out, B, scale);
}

// Round 13
// 115.999 us; speedup vs baseline: 1.0484x; 1.0484x over previous
//
#include <hip/hip_runtime.h>
#include <stdint.h>

#define N_PTS 256

typedef unsigned long long ull;
typedef float v2f __attribute__((ext_vector_type(2)));

// Single-inst DPP mov (old=0, bound_ctrl=1). row_ror has no invalid lanes, so
// the value is a pure rotate within each 16-lane row.
template<int CTRL>
__device__ __forceinline__ int dppmov(int x) {
    return __builtin_amdgcn_update_dpp(0, x, CTRL, 0xF, 0xF, true);
}

// All-lane min of f64 keys WITHIN each 16-lane row (4 independent rows served
// by the same 4 DPP stages -- the whole point: shared cross-lane ops).
// Keys are tiny positive denormal doubles -> v_min_f64 == uint64 min (AMD f64
// denormals always enabled; no NaNs possible, hi <= 0xFF).
__device__ __forceinline__ double rowmin16(double x) {
    #define STAGE(C) { \
        ull u = __double_as_longlong(x); \
        int lo = dppmov<C>((int)(unsigned)u); \
        int hi = dppmov<C>((int)(unsigned)(u >> 32)); \
        double r = __longlong_as_double(((ull)(unsigned)hi << 32) | (unsigned)lo); \
        x = fmin(x, r); }
    STAGE(0x121)  // row_ror:1
    STAGE(0x122)  // row_ror:2
    STAGE(0x124)  // row_ror:4
    STAGE(0x128)  // row_ror:8
    #undef STAGE
    return x;  // every lane of each row now holds its row's min
}

// Exact (dist, index) argmin over this row's 16 slots x 16 lanes.
// key = (dist_bits << 8) | k  with k = slot*16 + rl; used slots get hi |= 0x80
// (real dist_bits>>24 <= ~0x48, so poisoned always loses). Lexicographic min
// = reference's strict '<' first-min-wins, bit-exact.
__device__ __forceinline__ void reduce16(const float (&d)[16], unsigned used,
                                         unsigned rl16, unsigned& kk, unsigned& mu) {
    double kd[16];
    #pragma unroll
    for (int s = 0; s < 16; ++s) {
        unsigned du = __float_as_uint(d[s]);
        unsigned lo = (du << 8) | (unsigned)(s << 4) | rl16;
        unsigned hi = (du >> 24) | (((used >> s) & 1u) << 7);
        kd[s] = __longlong_as_double(((ull)hi << 32) | lo);
    }
    #pragma unroll
    for (int s = 0; s < 8; ++s) kd[s] = fmin(kd[s], kd[s + 8]);
    #pragma unroll
    for (int s = 0; s < 4; ++s) kd[s] = fmin(kd[s], kd[s + 4]);
    kd[0] = fmin(kd[0], kd[2]);
    kd[1] = fmin(kd[1], kd[3]);
    double km = rowmin16(fmin(kd[0], kd[1]));
    ull u = __double_as_longlong(km);
    unsigned lo = (unsigned)u, hi = (unsigned)(u >> 32);
    kk = lo & 0xFFu;
    mu = (lo >> 8) | (hi << 24);   // winner is always live -> poison bit 0
}

// se = min(m, BIG); if !(m < BIG) claim k=0 (matches reference exactly).
__device__ __forceinline__ void finalize(unsigned kk, unsigned mu,
                                         unsigned& k, float& se) {
    const unsigned BIG_U = 0x47810200u;  // __float_as_uint(66049.0f) = 257^2
    k  = (mu < BIG_U) ? kk : 0u;
    se = __uint_as_float(mu < BIG_U ? mu : BIG_U);
}

// Mark candidate sk used in this lane's 16-bit slot mask.
__device__ __forceinline__ void claim(unsigned sk, unsigned rl16, unsigned& used) {
    unsigned sbit = 1u << (sk >> 4);           // SALU
    used |= (rl16 == (sk & 15u)) ? sbit : 0u;  // v_cmp + cndmask + or
}

// One wave per batch; wave = 4 rows x 16 lanes; each row holds a replicated
// full candidate set (16 slots/lane, k = slot*16 + rl) and processes target
// j = 4g + row speculatively; collisions redone exactly.
__global__ __launch_bounds__(256, 2) void greedy_match_kernel(
    const float* __restrict__ input,
    const float* __restrict__ targets,
    float* __restrict__ out,
    int B, float scale)
{
    __shared__ v2f   tl[4][N_PTS];
    __shared__ float wsum[4];

    const unsigned lane = threadIdx.x & 63;
    const int      wid  = threadIdx.x >> 6;
    const int      b    = blockIdx.x * 4 + wid;
    const bool     vB   = (b < B);
    const int      cb   = vB ? b : 0;

    const unsigned rl16 = lane & 15u;     // lane within row
    const unsigned rowv = lane >> 4;      // row id (0..3)

    const v2f* pin = (const v2f*)(input   + (size_t)cb * (2 * N_PTS));
    const v2f* ptg = (const v2f*)(targets + (size_t)cb * (2 * N_PTS));

    // stage this wave's targets to LDS (read back per group: t[4g+row])
    #pragma unroll
    for (int c = 0; c < 4; ++c) {
        int idx = c * 64 + (int)lane;
        tl[wid][idx] = ptg[idx];
    }
    __syncthreads();
    const v2f* tlw = tl[wid];

    // replicated candidate registers: p[s] = point (s*16 + rl)
    v2f p[16];
    #pragma unroll
    for (int s = 0; s < 16; ++s) p[s] = pin[(s << 4) + rl16];

    unsigned used = 0u;
    float acc = 0.0f;

    {
        #pragma clang fp contract(off)
        v2f tcur = tlw[rowv];   // group 0 target for this row

        #pragma unroll 1
        for (int g = 0; g < 64; ++g) {
            v2f tnext = tlw[(((g + 1) & 63) << 2) + rowv];  // prefetch

            // distances: separate sub/mul/add rounding == fp32 numpy ref
            float d[16];
            #pragma unroll
            for (int s = 0; s < 16; ++s) {
                v2f q = tcur - p[s];
                v2f qq = q * q;
                d[s] = qq.x + qq.y;
            }

            unsigned kk, mu, kf; float sef;
            reduce16(d, used, rl16, kk, mu);
            finalize(kk, mu, kf, sef);
            unsigned vk = kf; float vse = sef;

            unsigned k0 = (unsigned)__builtin_amdgcn_readlane((int)vk, 0);
            unsigned k1 = (unsigned)__builtin_amdgcn_readlane((int)vk, 16);
            unsigned k2 = (unsigned)__builtin_amdgcn_readlane((int)vk, 32);
            unsigned k3 = (unsigned)__builtin_amdgcn_readlane((int)vk, 48);

            claim(k0, rl16, used);
            if (k1 == k0) {   // row1's pick consumed -> exact redo
                reduce16(d, used, rl16, kk, mu); finalize(kk, mu, kf, sef);
                bool upd = (rowv >= 1u);
                vk = upd ? kf : vk; vse = upd ? sef : vse;
                k1 = (unsigned)__builtin_amdgcn_readlane((int)vk, 16);
                k2 = (unsigned)__builtin_amdgcn_readlane((int)vk, 32);
                k3 = (unsigned)__builtin_amdgcn_readlane((int)vk, 48);
            }
            claim(k1, rl16, used);
            if (k2 == k0 || k2 == k1) {
                reduce16(d, used, rl16, kk, mu); finalize(kk, mu, kf, sef);
                bool upd = (rowv >= 2u);
                vk = upd ? kf : vk; vse = upd ? sef : vse;
                k2 = (unsigned)__builtin_amdgcn_readlane((int)vk, 32);
                k3 = (unsigned)__builtin_amdgcn_readlane((int)vk, 48);
            }
            claim(k2, rl16, used);
            if (k3 == k0 || k3 == k1 || k3 == k2) {
                reduce16(d, used, rl16, kk, mu); finalize(kk, mu, kf, sef);
                bool upd = (rowv >= 3u);
                vk = upd ? kf : vk; vse = upd ? sef : vse;
                k3 = (unsigned)__builtin_amdgcn_readlane((int)vk, 48);
            }
            claim(k3, rl16, used);

            acc += vse;   // row-uniform se of this row's target
            tcur = tnext;
        }
    }

    // sum the 4 row-subtotals (each row-uniform): xor16 swizzle + xor32 bpermute
    int t1 = __builtin_amdgcn_ds_swizzle(__float_as_int(acc), 0x401F);  // lane^16
    float a2 = acc + __int_as_float(t1);
    int t2 = __builtin_amdgcn_ds_bpermute((int)((lane ^ 32u) << 2), __float_as_int(a2));
    float tot = a2 + __int_as_float(t2);

    if (lane == 0) wsum[wid] = vB ? tot : 0.0f;
    __syncthreads();
    if (threadIdx.x == 0) {
        float s = (wsum[0] + wsum[1] + wsum[2] + wsum[3]) * scale;
        atomicAdd(out, s);
    }
}

extern "C" void kernel_launch(void* const* d_in, const int* in_sizes, int n_in,
                              void* d_out, int out_size, void* d_ws, size_t ws_size,
                              hipStream_t stream) {
    const float* input   = (const float*)d_in[0];
    const float* targets = (const float*)d_in[1];
    float* out = (float*)d_out;

    const int B = in_sizes[0] / (2 * N_PTS);
    const float scale = 1.0f / ((float)B * (float)(2 * N_PTS));

    // d_out is poisoned 0xAA before every call — zero it (graph-capturable).
    hipMemsetAsync(d_out, 0, sizeof(float) * (size_t)out_size, stream);

    const int blocks = (B + 3) / 4;  // 4 waves (4 batches) per 256-thread block
    greedy_match_kernel<<<blocks, 256, 0, stream>>>(input, targets, out, B, scale);
}